// Round 2
// baseline (258.013 us; speedup 1.0000x reference)
//
#include <hip/hip_runtime.h>

// Full 2D convolution: in (32,16,256,256) f32, shared 5x5 kernel, out (32,16,260,260) f32.
// out[n][y][x] = sum_{a,b in [0,5)} in[n][y-a][x-b] * w[a][b]
//
// R2: vertical register sliding window. Each thread computes a 4-wide x 10-tall
// output strip. A 5-row x 8-float input window lives in registers; each new
// output row loads ONE new input row (2 float4, clamped addresses + branch-free
// edge zeroing). Loads per output float4: 2.8 (was 10). FMAs unchanged.

#define IMG 256
#define OW  260
#define TXN 65           // float4s per output row
#define ROWS 10          // output rows per thread
#define STRIPS 26        // 260 / 10
#define NIMG 512         // 32*16 images
#define NTHREADS (NIMG * STRIPS * TXN)   // 865280 = 3380 * 256

__global__ __launch_bounds__(256) void conv_full_strip(
    const float* __restrict__ in, const float* __restrict__ w,
    float* __restrict__ out)
{
    // Shared 5x5 kernel — uniform, ends up in SGPRs / L1.
    float wt[25];
#pragma unroll
    for (int i = 0; i < 25; ++i) wt[i] = w[i];

    int idx = blockIdx.x * 256 + threadIdx.x;
    int tx4 = idx % TXN;
    int t   = idx / TXN;
    int s   = t % STRIPS;
    int n   = t / STRIPS;
    int y0  = s * ROWS;
    int x0  = tx4 * 4;

    // Clamped 16B-aligned load addresses; edge lanes zeroed branch-free.
    int xl = x0 - 4; if (xl < 0) xl = 0;
    int xh = x0;     if (xh > IMG - 4) xh = IMG - 4;
    const bool zL = (tx4 == 0);
    const bool zR = (tx4 == TXN - 1);

    const float* img  = in + (size_t)n * IMG * IMG;
    float*       outp = out + (((size_t)n * OW + y0) * TXN + tx4) * 4;

    float win[5][8];   // rows (y-4 .. y) of the 8-wide input slab

#define LOAD_ROW(slot, yy)                                          \
    do {                                                            \
        int _yy = (yy);                                             \
        if (_yy >= 0 && _yy < IMG) {                                \
            const float* _rb = img + _yy * IMG;                     \
            float4 _lo = *(const float4*)(_rb + xl);                \
            float4 _hi = *(const float4*)(_rb + xh);                \
            win[slot][0] = zL ? 0.f : _lo.x;                        \
            win[slot][1] = zL ? 0.f : _lo.y;                        \
            win[slot][2] = zL ? 0.f : _lo.z;                        \
            win[slot][3] = zL ? 0.f : _lo.w;                        \
            win[slot][4] = zR ? 0.f : _hi.x;                        \
            win[slot][5] = zR ? 0.f : _hi.y;                        \
            win[slot][6] = zR ? 0.f : _hi.z;                        \
            win[slot][7] = zR ? 0.f : _hi.w;                        \
        } else {                                                    \
            _Pragma("unroll")                                       \
            for (int _i = 0; _i < 8; ++_i) win[slot][_i] = 0.f;     \
        }                                                           \
    } while (0)

    // Prologue: rows y0-4 .. y0-1 into slots 0..3.
    LOAD_ROW(0, y0 - 4);
    LOAD_ROW(1, y0 - 3);
    LOAD_ROW(2, y0 - 2);
    LOAD_ROW(3, y0 - 1);

#pragma unroll
    for (int r = 0; r < ROWS; ++r) {
        LOAD_ROW((4 + r) % 5, y0 + r);   // new bottom row of the window

        float acc0 = 0.f, acc1 = 0.f, acc2 = 0.f, acc3 = 0.f;
#pragma unroll
        for (int a = 0; a < 5; ++a) {
            const float* vv = win[(4 + r - a) % 5];   // input row (y0+r-a)
#pragma unroll
            for (int b = 0; b < 5; ++b) {
                float wv = wt[a * 5 + b];
                acc0 = fmaf(vv[4 - b], wv, acc0);
                acc1 = fmaf(vv[5 - b], wv, acc1);
                acc2 = fmaf(vv[6 - b], wv, acc2);
                acc3 = fmaf(vv[7 - b], wv, acc3);
            }
        }
        *(float4*)(outp + r * (TXN * 4)) = make_float4(acc0, acc1, acc2, acc3);
    }
#undef LOAD_ROW
}

extern "C" void kernel_launch(void* const* d_in, const int* in_sizes, int n_in,
                              void* d_out, int out_size, void* d_ws, size_t ws_size,
                              hipStream_t stream) {
    const float* in = (const float*)d_in[0];   // 32*16*256*256 f32
    const float* w  = (const float*)d_in[1];   // 5*5 f32
    float* out = (float*)d_out;                // 32*16*260*260 f32

    int blocks = NTHREADS / 256;               // exactly 3380
    conv_full_strip<<<blocks, 256, 0, stream>>>(in, w, out);
}

// Round 3
// 243.827 us; speedup vs baseline: 1.0582x; 1.0582x over previous
//
#include <hip/hip_runtime.h>

// Full 2D convolution: in (32,16,256,256) f32, shared 5x5 kernel, out (32,16,260,260) f32.
// out[n][y][x] = sum_{a,b in [0,5)} in[n][y-a][x-b] * w[a][b]
//
// R3: latency-proofed strip kernel. Each thread computes a 4-wide x 10-tall
// output strip. ALL 14 input rows (2 float4 each, 28 independent loads with
// clamped always-valid addresses) are issued up front -> one waitcnt -> 
// branch-free masking (row-valid + column-edge folded into one cndmask pass)
// -> 1000 FMAs -> 10 float4 stores. No branches anywhere in the body.

#define IMG 256
#define OW  260
#define TXN 65           // float4s per output row
#define ROWS 10          // output rows per thread
#define WROWS 14         // input rows touched: ROWS + 4
#define STRIPS 26        // 260 / 10
#define NIMG 512         // 32*16 images
#define NTHREADS (NIMG * STRIPS * TXN)   // 865280 = 3380 * 256

__global__ __launch_bounds__(256, 3) void conv_full_strip3(
    const float* __restrict__ in, const float* __restrict__ w,
    float* __restrict__ out)
{
    float wt[25];
#pragma unroll
    for (int i = 0; i < 25; ++i) wt[i] = w[i];

    int idx = blockIdx.x * 256 + threadIdx.x;
    int tx4 = idx % TXN;
    int t   = idx / TXN;
    int s   = t % STRIPS;
    int n   = t / STRIPS;
    int y0  = s * ROWS;
    int x0  = tx4 * 4;

    // Clamped, always-in-bounds 16B-aligned load columns.
    int xl = x0 - 4; if (xl < 0) xl = 0;
    int xh = x0;     if (xh > IMG - 4) xh = IMG - 4;
    const bool zL = (tx4 == 0);         // cols x0-4..x0-1 left of image
    const bool zR = (tx4 == TXN - 1);   // cols 256..259 right of image

    const float* img = in + (size_t)n * IMG * IMG;

    // ---- Phase 1: issue all 28 independent loads (clamped rows, no branches).
    float4 rawL[WROWS], rawH[WROWS];
#pragma unroll
    for (int r = 0; r < WROWS; ++r) {
        int yy = y0 + r - 4;
        int yc = yy < 0 ? 0 : (yy > IMG - 1 ? IMG - 1 : yy);
        const float* rb = img + yc * IMG;
        rawL[r] = *(const float4*)(rb + xl);
        rawH[r] = *(const float4*)(rb + xh);
    }

    // ---- Phase 2: branch-free masking into the 8-wide window values.
    float v[WROWS][8];
#pragma unroll
    for (int r = 0; r < WROWS; ++r) {
        int yy = y0 + r - 4;
        bool rv = (yy >= 0) & (yy < IMG);
        bool mL = rv & !zL;
        bool mR = rv & !zR;
        v[r][0] = mL ? rawL[r].x : 0.f;
        v[r][1] = mL ? rawL[r].y : 0.f;
        v[r][2] = mL ? rawL[r].z : 0.f;
        v[r][3] = mL ? rawL[r].w : 0.f;
        v[r][4] = mR ? rawH[r].x : 0.f;
        v[r][5] = mR ? rawH[r].y : 0.f;
        v[r][6] = mR ? rawH[r].z : 0.f;
        v[r][7] = mR ? rawH[r].w : 0.f;
    }

    // ---- Phase 3: compute 10 output rows, store each as one float4.
    float* outp = out + (((size_t)n * OW + y0) * TXN + tx4) * 4;
#pragma unroll
    for (int r = 0; r < ROWS; ++r) {
        float acc0 = 0.f, acc1 = 0.f, acc2 = 0.f, acc3 = 0.f;
#pragma unroll
        for (int a = 0; a < 5; ++a) {
            const float* vv = v[r + 4 - a];   // input row y0 + r - a
#pragma unroll
            for (int b = 0; b < 5; ++b) {
                float wv = wt[a * 5 + b];
                acc0 = fmaf(vv[4 - b], wv, acc0);
                acc1 = fmaf(vv[5 - b], wv, acc1);
                acc2 = fmaf(vv[6 - b], wv, acc2);
                acc3 = fmaf(vv[7 - b], wv, acc3);
            }
        }
        *(float4*)(outp + (size_t)r * OW) = make_float4(acc0, acc1, acc2, acc3);
    }
}

extern "C" void kernel_launch(void* const* d_in, const int* in_sizes, int n_in,
                              void* d_out, int out_size, void* d_ws, size_t ws_size,
                              hipStream_t stream) {
    const float* in = (const float*)d_in[0];   // 32*16*256*256 f32
    const float* w  = (const float*)d_in[1];   // 5*5 f32
    float* out = (float*)d_out;                // 32*16*260*260 f32

    int blocks = NTHREADS / 256;               // exactly 3380
    conv_full_strip3<<<blocks, 256, 0, stream>>>(in, w, out);
}